// Round 13
// baseline (184.216 us; speedup 1.0000x reference)
//
#include <hip/hip_runtime.h>
#include <hip/hip_bf16.h>

// Self_Attention: conv1d(k=7,pad=3)+BN on q/k/v -> MHA (H=8, DH=64) -> LayerNorm
// R13: conv_bn v5 — 2-wave (128-thread) blocks, wave-tile 64s x 128co
// (12 ds_read_b128 per 32 MFMA = 0.375 vs 0.5) cutting the binding DS-read
// pipe 25%, grid stays 768 = 3 blocks/CU balanced. Same swizzle/ledger.
// attn(QBLK=128)/cast/prep/transpose/combine_ln frozen from R12.

#define B_ 4
#define S_ 2048
#define DIN_ 512
#define DOUT_ 512
#define H_ 8
#define DH_ 64
#define EPS_ 1e-5f
#define SP_ 2054   // S + 6 halo rows

using bf16x8 = __attribute__((ext_vector_type(8))) short;
using f32x4  = __attribute__((ext_vector_type(4))) float;

__device__ __forceinline__ unsigned short f2bf(float x) {
    union { float f; unsigned u; } v; v.f = x;
    unsigned r = v.u + 0x7FFF + ((v.u >> 16) & 1);
    return (unsigned short)(r >> 16);
}

__device__ __forceinline__ unsigned cvt2(float lo, float hi) {
    unsigned r;
    asm("v_cvt_pk_bf16_f32 %0, %1, %2" : "=v"(r) : "v"(lo), "v"(hi));
    return r;
}

__device__ __forceinline__ float fexp2(float x) {
    float r;
    asm("v_exp_f32 %0, %1" : "=v"(r) : "v"(x));
    return r;
}

__device__ __forceinline__ float bf2f(unsigned short u) {
    union { unsigned u; float f; } v; v.u = ((unsigned)u) << 16;
    return v.f;
}

typedef __attribute__((address_space(1))) const unsigned int GU32;
typedef __attribute__((address_space(3))) unsigned int LU32;
__device__ __forceinline__ void gl_lds16(const void* g, void* l) {
    __builtin_amdgcn_global_load_lds((GU32*)g, (LU32*)l, 16, 0, 0);
}

// ---------------- kernel 0: cast q/k/v f32 -> bf16 padded [3][4][SP][512] ----
__global__ void cast_x(const float* __restrict__ q, const float* __restrict__ k,
                       const float* __restrict__ v, unsigned short* __restrict__ xb) {
    int i = blockIdx.x * 256 + threadIdx.x;
    int row = i >> 6;
    int cin = (i & 63) * 8;
    int tb = row / SP_;
    int pr = row - tb * SP_;
    int tensor = tb >> 2;
    int b = tb & 3;
    unsigned short* dst = xb + (size_t)row * DIN_ + cin;
    if (pr < 3 || pr >= SP_ - 3) {
        *reinterpret_cast<uint4*>(dst) = make_uint4(0, 0, 0, 0);
    } else {
        const float* src = (tensor == 0 ? q : (tensor == 1 ? k : v)) +
                           ((size_t)b * S_ + (pr - 3)) * DIN_ + cin;
        float4 a0 = *reinterpret_cast<const float4*>(src);
        float4 a1 = *reinterpret_cast<const float4*>(src + 4);
        uint4 o;
        o.x = cvt2(a0.x, a0.y); o.y = cvt2(a0.z, a0.w);
        o.z = cvt2(a1.x, a1.y); o.w = cvt2(a1.z, a1.w);
        *reinterpret_cast<uint4*>(dst) = o;
    }
}

// ---------------- kernel 1: fold BN into weights, cast to bf16 [t][co][ci] ----
__global__ void prep_w(const float* __restrict__ w, const float* __restrict__ cb,
                       const float* __restrict__ gamma, const float* __restrict__ beta,
                       const float* __restrict__ mean, const float* __restrict__ var,
                       unsigned short* __restrict__ w_eff, float* __restrict__ b_eff) {
    int gid = blockIdx.x * blockDim.x + threadIdx.x;
    if (gid < DOUT_) {
        float sc = gamma[gid] * rsqrtf(var[gid] + EPS_);
        b_eff[gid] = (cb[gid] - mean[gid]) * sc + beta[gid];
    }
    int total = 7 * DOUT_ * DIN_;
    for (int i = gid; i < total; i += gridDim.x * blockDim.x) {
        int t = i / (DOUT_ * DIN_);
        int rem = i - t * (DOUT_ * DIN_);
        int co = rem >> 9;
        int ci = rem & 511;
        float sc = gamma[co] * rsqrtf(var[co] + EPS_);
        w_eff[i] = f2bf(w[(co * DIN_ + ci) * 7 + t] * sc);
    }
}

// ---------------- kernel 2: conv+BN implicit GEMM v5 -------------------------
// Block: 128 s-rows x 128 co, 2 waves, each 64s x 128co (4x8 frags, K=32).
// A LDS dbuf [2][192][32] (6 gl_lds/wave per cc); B tri-buf [3][128][32]
// (4 gl_lds/wave per phase). Swizzle ^((r>>1)&3). 112 phases.
// Ledger/wave: t<6 issue 4, vmcnt(4); t==6 issue 10, vmcnt(10); last vmcnt(0).
__global__ __launch_bounds__(128, 2) void conv_bn(
        const unsigned short* __restrict__ xb,
        const unsigned short* __restrict__ w_eff,
        const float* __restrict__ b_eff,
        unsigned short* __restrict__ out3) {
    __shared__ alignas(16) unsigned short As[2][192 * 32];
    __shared__ alignas(16) unsigned short Bs[3][128 * 32];

    int orig = blockIdx.x;
    int bid = (orig & 7) * 96 + (orig >> 3);   // XCD-chunked, 768 = 8*96
    int tensor = bid >> 8;
    int rem = bid & 255;
    int batch = rem >> 6;
    int stile = (rem >> 2) & 15;
    int cotile = rem & 3;
    int s0 = stile * 128;
    int co0 = cotile * 128;

    const unsigned short* xp = xb + (size_t)(tensor * 4 + batch) * SP_ * DIN_;
    unsigned short* out = out3 + (size_t)tensor * (B_ * S_ * DOUT_) +
                          (size_t)batch * S_ * DOUT_;

    const int tid = threadIdx.x;
    const int l = tid & 63;
    const int wv = tid >> 6;          // 0 or 1
    const int g = l >> 4;
    const int c16 = l & 15;
    const int wrow = wv * 64;

    const int dr4 = l >> 2;
    const int sch = ((l & 3) ^ ((l >> 3) & 3)) << 3;

#define STAGE_A(cc, buf) do {                                                   \
        _Pragma("unroll")                                                       \
        for (int j = 0; j < 6; ++j) {                                           \
            int r0 = (wv * 6 + j) * 16;                                         \
            int rs = r0 + dr4; if (rs > 133) rs = 133;                          \
            gl_lds16(xp + (size_t)(s0 + rs) * DIN_ + (cc) * 32 + sch,           \
                     &As[buf][r0 * 32]);                                        \
        }                                                                       \
    } while (0)

#define STAGE_B(cc, t, buf) do {                                                \
        const unsigned short* wp = w_eff + (size_t)(t) * (DOUT_ * DIN_) +       \
                                   (cc) * 32;                                   \
        _Pragma("unroll")                                                       \
        for (int j = 0; j < 4; ++j) {                                           \
            int r0 = (wv * 4 + j) * 16;                                         \
            gl_lds16(wp + (size_t)(co0 + r0 + dr4) * DIN_ + sch,                \
                     &Bs[buf][r0 * 32]);                                        \
        }                                                                       \
    } while (0)

    f32x4 acc[4][8] = {};

    STAGE_A(0, 0);
    STAGE_B(0, 0, 0);
    int bcur = 0;

    for (int cc = 0; cc < 16; ++cc) {
        const int ca = cc & 1;
        for (int t = 0; t < 7; ++t) {
            int bnext = (bcur == 2) ? 0 : bcur + 1;
            if (t < 6) {
                STAGE_B(cc, t + 1, bnext);
                asm volatile("s_waitcnt vmcnt(4)" ::: "memory");
            } else if (cc < 15) {
                STAGE_B(cc + 1, 0, bnext);
                STAGE_A(cc + 1, ca ^ 1);
                asm volatile("s_waitcnt vmcnt(10)" ::: "memory");
            } else {
                asm volatile("s_waitcnt vmcnt(0)" ::: "memory");
            }
            __builtin_amdgcn_s_barrier();

            const unsigned short* Ab = &As[ca][0];
            const unsigned short* Bb = &Bs[bcur][0];
            bf16x8 af[4], bfv[8];
#pragma unroll
            for (int m = 0; m < 4; ++m) {
                int r = wrow + m * 16 + c16 + t;
                af[m] = *reinterpret_cast<const bf16x8*>(
                    &Ab[r * 32 + ((g ^ ((r >> 1) & 3)) << 3)]);
            }
#pragma unroll
            for (int n = 0; n < 8; ++n) {
                int rb = n * 16 + c16;
                bfv[n] = *reinterpret_cast<const bf16x8*>(
                    &Bb[rb * 32 + ((g ^ ((rb >> 1) & 3)) << 3)]);
            }
            __builtin_amdgcn_s_setprio(1);
#pragma unroll
            for (int m = 0; m < 4; ++m)
#pragma unroll
                for (int n = 0; n < 8; ++n)
                    acc[m][n] = __builtin_amdgcn_mfma_f32_16x16x32_bf16(
                        af[m], bfv[n], acc[m][n], 0, 0, 0);
            __builtin_amdgcn_s_setprio(0);
            bcur = bnext;
        }
    }

    // Q branch: fold 1/sqrt(DH) * log2(e) so attn softmax runs in exp2 domain
    float osc = (tensor == 0) ? 0.125f * 1.44269504f : 1.0f;
#pragma unroll
    for (int m = 0; m < 4; ++m) {
        int rowb = s0 + wrow + m * 16 + 4 * g;
#pragma unroll
        for (int n = 0; n < 8; ++n) {
            int col = co0 + n * 16 + c16;
            float be = b_eff[col];
#pragma unroll
            for (int ri = 0; ri < 4; ++ri)
                out[(size_t)(rowb + ri) * DOUT_ + col] =
                    f2bf((acc[m][n][ri] + be) * osc);
        }
    }
#undef STAGE_A
#undef STAGE_B
}

// ---------------- kernel 2b: transpose V per (b,h): [S][DH] -> [DH][S] --------
__global__ void transpose_v(const unsigned short* __restrict__ vh,
                            unsigned short* __restrict__ vt) {
    __shared__ alignas(16) unsigned short T[64 * 64];
    int bid = blockIdx.x;
    int stile = bid & 31;
    int bh = bid >> 5;
    int b = bh >> 3;
    int h = bh & 7;
    int s0 = stile * 64;
    const unsigned short* src = vh + ((size_t)b * S_ + s0) * DOUT_ + h * DH_;
    unsigned short* dst = vt + (size_t)bh * DH_ * S_ + s0;
    int tid = threadIdx.x;
#pragma unroll
    for (int it = 0; it < 2; ++it) {
        int idx = tid + it * 256;
        int s = idx >> 3, dhc = idx & 7;
        uint4 val = *reinterpret_cast<const uint4*>(&src[(size_t)s * DOUT_ + dhc * 8]);
        *reinterpret_cast<uint4*>(&T[s * 64 + ((dhc ^ (s & 7) ^ ((s >> 3) & 7)) << 3)]) = val;
    }
    __syncthreads();
#pragma unroll
    for (int it = 0; it < 2; ++it) {
        int idx = tid + it * 256;
        int dh = idx >> 3, sc = idx & 7;
        unsigned short tmp[8];
#pragma unroll
        for (int j = 0; j < 8; ++j) {
            int s = sc * 8 + j;
            tmp[j] = T[s * 64 + (((dh >> 3) ^ (s & 7) ^ ((s >> 3) & 7)) << 3) + (dh & 7)];
        }
        *reinterpret_cast<uint4*>(&dst[(size_t)dh * S_ + sc * 8]) =
            *reinterpret_cast<const uint4*>(tmp);
    }
}

// ---------------- kernel 3: flash attention, QBLK=128, K-split x2 (R12) ------
__global__ __launch_bounds__(256, 4) void attn(const unsigned short* __restrict__ qh,
                     const unsigned short* __restrict__ kh,
                     const unsigned short* __restrict__ vt,
                     unsigned short* __restrict__ part,
                     float2* __restrict__ ml) {
    __shared__ alignas(16) unsigned short Ks[2][64 * 64];
    __shared__ alignas(16) unsigned short Vs[2][64 * 64];

    const int tid = threadIdx.x;
    const int l = tid & 63;
    const int wv = tid >> 6;
    const int g = l >> 4;
    const int c16 = l & 15;

    const int bid = blockIdx.x;
    const int ks = bid >> 9;
    const int r9 = bid & 511;
    const int qt = r9 & 15;
    const int bh = r9 >> 4;
    const int b = bh >> 3;
    const int h = bh & 7;
    const int s0 = qt * 128;

    const unsigned short* qp = qh + (size_t)b * S_ * DOUT_ + h * DH_;
    const unsigned short* kp = kh + (size_t)b * S_ * DOUT_ + h * DH_;
    const unsigned short* vp = vt + (size_t)bh * DH_ * S_;

    bf16x8 qfA[2], qfB[2];
    {
        int rowA = s0 + wv * 16 + c16;
        int rowB = rowA + 64;
        qfA[0] = *reinterpret_cast<const bf16x8*>(&qp[(size_t)rowA * DOUT_ + 8 * g]);
        qfA[1] = *reinterpret_cast<const bf16x8*>(&qp[(size_t)rowA * DOUT_ + 32 + 8 * g]);
        qfB[0] = *reinterpret_cast<const bf16x8*>(&qp[(size_t)rowB * DOUT_ + 8 * g]);
        qfB[1] = *reinterpret_cast<const bf16x8*>(&qp[(size_t)rowB * DOUT_ + 32 + 8 * g]);
    }

    const int l3 = l >> 3;
    const int kchunk8 = ((l & 7) ^ l3) * 8;

#define STAGE(kt, buf) do {                                                          \
        const unsigned short* kgp = kp + (size_t)(kt) * 64 * DOUT_;                  \
        const unsigned short* vgp = vp + (size_t)(kt) * 64;                          \
        _Pragma("unroll")                                                            \
        for (int i = 0; i < 2; ++i) {                                                \
            int K0 = wv * 16 + i * 8;                                                \
            gl_lds16(kgp + (size_t)(K0 + l3) * DOUT_ + kchunk8, &Ks[buf][K0 * 64]);  \
            gl_lds16(vgp + (size_t)(K0 + l3) * S_   + kchunk8, &Vs[buf][K0 * 64]);   \
        }                                                                            \
    } while (0)

    f32x4 oaccA[4] = {}, oaccB[4] = {};
    float mrowA = -1e30f, lrowA = 0.f;
    float mrowB = -1e30f, lrowB = 0.f;

    const int sA = ((l & 16) << 1) | c16;
    const int sB = sA + 16;
    const bool hi = (l & 32) != 0;

    const int t0 = ks * 16;
    STAGE(t0, 0);

#define SOFTMAX_GRP(sf, mrow, lrow, oacc, pk) do {                               \
        float u0 = fmaxf(fmaxf(sf[0][0], sf[0][1]), fmaxf(sf[0][2], sf[0][3]));  \
        float u1 = fmaxf(fmaxf(sf[1][0], sf[1][1]), fmaxf(sf[1][2], sf[1][3]));  \
        float u2 = fmaxf(fmaxf(sf[2][0], sf[2][1]), fmaxf(sf[2][2], sf[2][3]));  \
        float u3 = fmaxf(fmaxf(sf[3][0], sf[3][1]), fmaxf(sf[3][2], sf[3][3]));  \
        float m0 = fmaxf(fmaxf(u0, u1), fmaxf(u2, u3));                          \
        m0 = fmaxf(m0, __shfl_xor(m0, 16, 64));                                  \
        m0 = fmaxf(m0, __shfl_xor(m0, 32, 64));                                  \
        if (!__all(m0 <= mrow + 8.f)) {                                          \
            float mnew = fmaxf(mrow, m0);                                        \
            float corr = fexp2(mrow - mnew);                                     \
            mrow = mnew;                                                         \
            lrow *= corr;                                                        \
            _Pragma("unroll")                                                    \
            for (int n = 0; n < 4; ++n) {                                        \
                oacc[n][0] *= corr; oacc[n][1] *= corr;                          \
                oacc[n][2] *= corr; oacc[n][3] *= corr;                          \
            }                                                                    \
        }                                                                        \
        float rsacc = 0.f;                                                       \
        _Pragma("unroll")                                                        \
        for (int n = 0; n < 4; ++n) {                                            \
            float p0 = fexp2(sf[n][0] - mrow);                                   \
            float p1 = fexp2(sf[n][1] - mrow);                                   \
            float p2 = fexp2(sf[n][2] - mrow);                                   \
            float p3 = fexp2(sf[n][3] - mrow);                                   \
            rsacc += (p0 + p1) + (p2 + p3);                                      \
            pk[n][0] = cvt2(p0, p1);                                             \
            pk[n][1] = cvt2(p2, p3);                                             \
        }                                                                        \
        rsacc += __shfl_xor(rsacc, 16, 64);                                      \
        rsacc += __shfl_xor(rsacc, 32, 64);                                      \
        lrow += rsacc;                                                           \
    } while (0)

#define BUILD_PU(pk, kk, pu) do {                                                \
        unsigned a0 = __shfl((int)pk[2 * (kk)][0], sA, 64);                      \
        unsigned a1 = __shfl((int)pk[2 * (kk)][1], sA, 64);                      \
        unsigned a2 = __shfl((int)pk[2 * (kk)][0], sB, 64);                      \
        unsigned a3 = __shfl((int)pk[2 * (kk)][1], sB, 64);                      \
        unsigned b0 = __shfl((int)pk[2 * (kk) + 1][0], sA, 64);                  \
        unsigned b1 = __shfl((int)pk[2 * (kk) + 1][1], sA, 64);                  \
        unsigned b2 = __shfl((int)pk[2 * (kk) + 1][0], sB, 64);                  \
        unsigned b3 = __shfl((int)pk[2 * (kk) + 1][1], sB, 64);                  \
        pu.w[0] = hi ? b0 : a0;                                                  \
        pu.w[1] = hi ? b1 : a1;                                                  \
        pu.w[2] = hi ? b2 : a2;                                                  \
        pu.w[3] = hi ? b3 : a3;                                                  \
    } while (0)

    for (int i = 0; i < 16; ++i) {
        const int cur = i & 1;
        if (i + 1 < 16) {
            STAGE(t0 + i + 1, 1 - cur);
            asm volatile("s_waitcnt vmcnt(4)" ::: "memory");
        } else {
            asm volatile("s_waitcnt vmcnt(0)" ::: "memory");
        }
        __builtin_amdgcn_s_barrier();

        const char* KsB = (const char*)&Ks[cur][0];
        f32x4 sfA[4] = {}, sfB[4] = {};
#pragma unroll
        for (int kk = 0; kk < 2; ++kk) {
            bf16x8 kf[4];
#pragma unroll
            for (int n = 0; n < 4; ++n)
                kf[n] = *reinterpret_cast<const bf16x8*>(
                    KsB + (n * 16 + c16) * 128 + (((4 * kk + g) ^ (l & 7)) << 4));
            __builtin_amdgcn_s_setprio(1);
#pragma unroll
            for (int n = 0; n < 4; ++n) {
                sfA[n] = __builtin_amdgcn_mfma_f32_16x16x32_bf16(kf[n], qfA[kk], sfA[n], 0, 0, 0);
                sfB[n] = __builtin_amdgcn_mfma_f32_16x16x32_bf16(kf[n], qfB[kk], sfB[n], 0, 0, 0);
            }
            __builtin_amdgcn_s_setprio(0);
        }

        unsigned pkA[4][2], pkB[4][2];
        SOFTMAX_GRP(sfA, mrowA, lrowA, oaccA, pkA);
        SOFTMAX_GRP(sfB, mrowB, lrowB, oaccB, pkB);

        const char* VsB = (const char*)&Vs[cur][0];
#pragma unroll
        for (int kk = 0; kk < 2; ++kk) {
            union { unsigned w[4]; bf16x8 v; } puA, puB;
            BUILD_PU(pkA, kk, puA);
            BUILD_PU(pkB, kk, puB);
            bf16x8 vfr[4];
#pragma unroll
            for (int n = 0; n < 4; ++n)
                vfr[n] = *reinterpret_cast<const bf16x8*>(
                    VsB + (n * 16 + c16) * 128 + (((4 * kk + g) ^ (l & 7)) << 4));
            __builtin_amdgcn_s_setprio(1);
#pragma unroll
            for (int n = 0; n < 4; ++n) {
                oaccA[n] = __builtin_amdgcn_mfma_f32_16x16x32_bf16(vfr[n], puA.v, oaccA[n], 0, 0, 0);
                oaccB[n] = __builtin_amdgcn_mfma_f32_16x16x32_bf16(vfr[n], puB.v, oaccB[n], 0, 0, 0);
            }
            __builtin_amdgcn_s_setprio(0);
        }
        __builtin_amdgcn_s_barrier();
    }

    {
        int rowA = s0 + wv * 16 + c16;
        int rowB = rowA + 64;
        unsigned short* ppA = part + (((size_t)ks * 32 + bh) * S_ + rowA) * DH_;
        unsigned short* ppB = part + (((size_t)ks * 32 + bh) * S_ + rowB) * DH_;
#pragma unroll
        for (int n = 0; n < 4; ++n) {
            uint2 wA, wB;
            wA.x = cvt2(oaccA[n][0], oaccA[n][1]);
            wA.y = cvt2(oaccA[n][2], oaccA[n][3]);
            wB.x = cvt2(oaccB[n][0], oaccB[n][1]);
            wB.y = cvt2(oaccB[n][2], oaccB[n][3]);
            *reinterpret_cast<uint2*>(&ppA[n * 16 + 4 * g]) = wA;
            *reinterpret_cast<uint2*>(&ppB[n * 16 + 4 * g]) = wB;
        }
        if (g == 0) {
            ml[((size_t)ks * 32 + bh) * S_ + rowA] = make_float2(mrowA, lrowA);
            ml[((size_t)ks * 32 + bh) * S_ + rowB] = make_float2(mrowB, lrowB);
        }
    }
#undef STAGE
#undef SOFTMAX_GRP
#undef BUILD_PU
}

// ---------------- kernel 4: combine K-split partials + LayerNorm -------------
__global__ void combine_ln(const unsigned short* __restrict__ part,
                           const float2* __restrict__ ml,
                           const float* __restrict__ gamma,
                           const float* __restrict__ beta,
                           float* __restrict__ out) {
    int tid = threadIdx.x;
    int lane = tid & 63;
    int wv = tid >> 6;
    int row = blockIdx.x * 4 + wv;          // 0 .. B*S-1
    int b = row >> 11;
    int q = row & 2047;
    int h = lane >> 3;
    int dh0 = (lane & 7) * 8;

    size_t idx0 = ((size_t)(b * 8 + h)) * S_ + q;
    size_t idx1 = ((size_t)32 + b * 8 + h) * S_ + q;
    uint4 r0 = *reinterpret_cast<const uint4*>(&part[idx0 * DH_ + dh0]);
    uint4 r1 = *reinterpret_cast<const uint4*>(&part[idx1 * DH_ + dh0]);
    float2 ml0 = ml[idx0];
    float2 ml1 = ml[idx1];

    float m = fmaxf(ml0.x, ml1.x);
    float w0 = fexp2(ml0.x - m);
    float w1 = fexp2(ml1.x - m);
    float linv = 1.0f / (w0 * ml0.y + w1 * ml1.y);

    const unsigned short* e0 = reinterpret_cast<const unsigned short*>(&r0);
    const unsigned short* e1 = reinterpret_cast<const unsigned short*>(&r1);
    float o[8];
    float s = 0.f, sq = 0.f;
#pragma unroll
    for (int j = 0; j < 8; ++j) {
        float v = (w0 * bf2f(e0[j]) + w1 * bf2f(e1[j])) * linv;
        o[j] = v;
        s += v;
        sq += v * v;
    }
    for (int off = 1; off < 64; off <<= 1) {
        s += __shfl_xor(s, off, 64);
        sq += __shfl_xor(sq, off, 64);
    }
    float mu = s * (1.0f / 512.0f);
    float var = sq * (1.0f / 512.0f) - mu * mu;
    float rstd = rsqrtf(fmaxf(var, 0.f) + EPS_);

    int f0 = lane * 8;
    float4 g0 = *reinterpret_cast<const float4*>(&gamma[f0]);
    float4 g1 = *reinterpret_cast<const float4*>(&gamma[f0 + 4]);
    float4 b0 = *reinterpret_cast<const float4*>(&beta[f0]);
    float4 b1 = *reinterpret_cast<const float4*>(&beta[f0 + 4]);
    float4 o0, o1;
    o0.x = (o[0] - mu) * rstd * g0.x + b0.x;
    o0.y = (o[1] - mu) * rstd * g0.y + b0.y;
    o0.z = (o[2] - mu) * rstd * g0.z + b0.z;
    o0.w = (o[3] - mu) * rstd * g0.w + b0.w;
    o1.x = (o[4] - mu) * rstd * g1.x + b1.x;
    o1.y = (o[5] - mu) * rstd * g1.y + b1.y;
    o1.z = (o[6] - mu) * rstd * g1.z + b1.z;
    o1.w = (o[7] - mu) * rstd * g1.w + b1.w;
    float* op = out + (size_t)row * DOUT_ + f0;
    *reinterpret_cast<float4*>(op) = o0;
    *reinterpret_cast<float4*>(op + 4) = o1;
}

extern "C" void kernel_launch(void* const* d_in, const int* in_sizes, int n_in,
                              void* d_out, int out_size, void* d_ws, size_t ws_size,
                              hipStream_t stream) {
    const float* q        = (const float*)d_in[0];
    const float* k        = (const float*)d_in[1];
    const float* v        = (const float*)d_in[2];
    const float* conv_w   = (const float*)d_in[3];
    const float* conv_b   = (const float*)d_in[4];
    const float* bn_gamma = (const float*)d_in[5];
    const float* bn_beta  = (const float*)d_in[6];
    const float* bn_mean  = (const float*)d_in[7];
    const float* bn_var   = (const float*)d_in[8];
    const float* ln_gamma = (const float*)d_in[9];
    const float* ln_beta  = (const float*)d_in[10];

    unsigned short* qh    = (unsigned short*)d_ws;
    unsigned short* kh    = qh + (size_t)B_ * S_ * DOUT_;
    unsigned short* vh    = kh + (size_t)B_ * S_ * DOUT_;
    unsigned short* w_eff = vh + (size_t)B_ * S_ * DOUT_;
    float* b_eff          = (float*)(w_eff + (size_t)7 * DOUT_ * DIN_);
    unsigned short* xb    = (unsigned short*)(b_eff + DOUT_);
    unsigned short* vt    = xb;   // alias: vt written only after conv consumed xb
    unsigned short* part  = xb + (size_t)12 * SP_ * DIN_;
    float2* ml            = (float2*)(part + (size_t)2 * B_ * H_ * S_ * DH_);

    float* out = (float*)d_out;

    cast_x<<<dim3(6162), dim3(256), 0, stream>>>(q, k, v, xb);
    prep_w<<<dim3(7168), dim3(256), 0, stream>>>(conv_w, conv_b, bn_gamma, bn_beta,
                                                 bn_mean, bn_var, w_eff, b_eff);
    conv_bn<<<dim3(768), dim3(128), 0, stream>>>(xb, w_eff, b_eff, qh);
    transpose_v<<<dim3(1024), dim3(256), 0, stream>>>(vh, vt);
    attn<<<dim3(1024), dim3(256), 0, stream>>>(qh, kh, vt, part, ml);
    combine_ln<<<dim3(2048), dim3(256), 0, stream>>>(part, ml, ln_gamma, ln_beta, out);
}

// Round 15
// 178.421 us; speedup vs baseline: 1.0325x; 1.0325x over previous
//
#include <hip/hip_runtime.h>
#include <hip/hip_bf16.h>

// Self_Attention: conv1d(k=7,pad=3)+BN on q/k/v -> MHA (H=8, DH=64) -> LayerNorm
// R15 = exact revert to R12 (best passing config, 179.15us):
// conv_bn v4 (4 waves, 64x64 wave tiles, A dbuf + B TRI-buf — dbuf races with
// laggard waves across the phase barrier, proven by R14's absmax=1.49),
// attn QBLK=128 + K-split x2, combine_ln fused epilogue.

#define B_ 4
#define S_ 2048
#define DIN_ 512
#define DOUT_ 512
#define H_ 8
#define DH_ 64
#define EPS_ 1e-5f
#define SP_ 2054   // S + 6 halo rows

using bf16x8 = __attribute__((ext_vector_type(8))) short;
using f32x4  = __attribute__((ext_vector_type(4))) float;

__device__ __forceinline__ unsigned short f2bf(float x) {
    union { float f; unsigned u; } v; v.f = x;
    unsigned r = v.u + 0x7FFF + ((v.u >> 16) & 1);
    return (unsigned short)(r >> 16);
}

__device__ __forceinline__ unsigned cvt2(float lo, float hi) {
    unsigned r;
    asm("v_cvt_pk_bf16_f32 %0, %1, %2" : "=v"(r) : "v"(lo), "v"(hi));
    return r;
}

__device__ __forceinline__ float fexp2(float x) {
    float r;
    asm("v_exp_f32 %0, %1" : "=v"(r) : "v"(x));
    return r;
}

__device__ __forceinline__ float bf2f(unsigned short u) {
    union { unsigned u; float f; } v; v.u = ((unsigned)u) << 16;
    return v.f;
}

typedef __attribute__((address_space(1))) const unsigned int GU32;
typedef __attribute__((address_space(3))) unsigned int LU32;
__device__ __forceinline__ void gl_lds16(const void* g, void* l) {
    __builtin_amdgcn_global_load_lds((GU32*)g, (LU32*)l, 16, 0, 0);
}

// ---------------- kernel 0: cast q/k/v f32 -> bf16 padded [3][4][SP][512] ----
__global__ void cast_x(const float* __restrict__ q, const float* __restrict__ k,
                       const float* __restrict__ v, unsigned short* __restrict__ xb) {
    int i = blockIdx.x * 256 + threadIdx.x;
    int row = i >> 6;
    int cin = (i & 63) * 8;
    int tb = row / SP_;
    int pr = row - tb * SP_;
    int tensor = tb >> 2;
    int b = tb & 3;
    unsigned short* dst = xb + (size_t)row * DIN_ + cin;
    if (pr < 3 || pr >= SP_ - 3) {
        *reinterpret_cast<uint4*>(dst) = make_uint4(0, 0, 0, 0);
    } else {
        const float* src = (tensor == 0 ? q : (tensor == 1 ? k : v)) +
                           ((size_t)b * S_ + (pr - 3)) * DIN_ + cin;
        float4 a0 = *reinterpret_cast<const float4*>(src);
        float4 a1 = *reinterpret_cast<const float4*>(src + 4);
        uint4 o;
        o.x = cvt2(a0.x, a0.y); o.y = cvt2(a0.z, a0.w);
        o.z = cvt2(a1.x, a1.y); o.w = cvt2(a1.z, a1.w);
        *reinterpret_cast<uint4*>(dst) = o;
    }
}

// ---------------- kernel 1: fold BN into weights, cast to bf16 [t][co][ci] ----
__global__ void prep_w(const float* __restrict__ w, const float* __restrict__ cb,
                       const float* __restrict__ gamma, const float* __restrict__ beta,
                       const float* __restrict__ mean, const float* __restrict__ var,
                       unsigned short* __restrict__ w_eff, float* __restrict__ b_eff) {
    int gid = blockIdx.x * blockDim.x + threadIdx.x;
    if (gid < DOUT_) {
        float sc = gamma[gid] * rsqrtf(var[gid] + EPS_);
        b_eff[gid] = (cb[gid] - mean[gid]) * sc + beta[gid];
    }
    int total = 7 * DOUT_ * DIN_;
    for (int i = gid; i < total; i += gridDim.x * blockDim.x) {
        int t = i / (DOUT_ * DIN_);
        int rem = i - t * (DOUT_ * DIN_);
        int co = rem >> 9;
        int ci = rem & 511;
        float sc = gamma[co] * rsqrtf(var[co] + EPS_);
        w_eff[i] = f2bf(w[(co * DIN_ + ci) * 7 + t] * sc);
    }
}

// ---------------- kernel 2: conv+BN implicit GEMM v4 (R12-proven) ------------
__global__ __launch_bounds__(256, 3) void conv_bn(
        const unsigned short* __restrict__ xb,
        const unsigned short* __restrict__ w_eff,
        const float* __restrict__ b_eff,
        unsigned short* __restrict__ out3) {
    __shared__ alignas(16) unsigned short As[2][192 * 32];
    __shared__ alignas(16) unsigned short Bs[3][128 * 32];

    int orig = blockIdx.x;
    int bid = (orig & 7) * 96 + (orig >> 3);   // XCD-chunked, 768 = 8*96
    int tensor = bid >> 8;
    int rem = bid & 255;
    int batch = rem >> 6;
    int stile = (rem >> 2) & 15;
    int cotile = rem & 3;
    int s0 = stile * 128;
    int co0 = cotile * 128;

    const unsigned short* xp = xb + (size_t)(tensor * 4 + batch) * SP_ * DIN_;
    unsigned short* out = out3 + (size_t)tensor * (B_ * S_ * DOUT_) +
                          (size_t)batch * S_ * DOUT_;

    const int tid = threadIdx.x;
    const int l = tid & 63;
    const int wv = tid >> 6;
    const int g = l >> 4;
    const int c16 = l & 15;
    const int wrow = (wv >> 1) * 64;
    const int wcol = (wv & 1) * 64;

    const int dr4 = l >> 2;
    const int sch = ((l & 3) ^ ((l >> 3) & 3)) << 3;

#define STAGE_A(cc, buf) do {                                                   \
        _Pragma("unroll")                                                       \
        for (int j = 0; j < 3; ++j) {                                           \
            int r0 = (wv * 3 + j) * 16;                                         \
            int rs = r0 + dr4; if (rs > 133) rs = 133;                          \
            gl_lds16(xp + (size_t)(s0 + rs) * DIN_ + (cc) * 32 + sch,           \
                     &As[buf][r0 * 32]);                                        \
        }                                                                       \
    } while (0)

#define STAGE_B(cc, t, buf) do {                                                \
        const unsigned short* wp = w_eff + (size_t)(t) * (DOUT_ * DIN_) +       \
                                   (cc) * 32;                                   \
        _Pragma("unroll")                                                       \
        for (int j = 0; j < 2; ++j) {                                           \
            int r0 = (wv * 2 + j) * 16;                                         \
            gl_lds16(wp + (size_t)(co0 + r0 + dr4) * DIN_ + sch,                \
                     &Bs[buf][r0 * 32]);                                        \
        }                                                                       \
    } while (0)

    f32x4 acc[4][4] = {};

    STAGE_A(0, 0);
    STAGE_B(0, 0, 0);
    int bcur = 0;

    for (int cc = 0; cc < 16; ++cc) {
        const int ca = cc & 1;
        for (int t = 0; t < 7; ++t) {
            int bnext = (bcur == 2) ? 0 : bcur + 1;
            if (t < 6) {
                STAGE_B(cc, t + 1, bnext);
                asm volatile("s_waitcnt vmcnt(2)" ::: "memory");
            } else if (cc < 15) {
                STAGE_B(cc + 1, 0, bnext);
                STAGE_A(cc + 1, ca ^ 1);
                asm volatile("s_waitcnt vmcnt(5)" ::: "memory");
            } else {
                asm volatile("s_waitcnt vmcnt(0)" ::: "memory");
            }
            __builtin_amdgcn_s_barrier();

            const unsigned short* Ab = &As[ca][0];
            const unsigned short* Bb = &Bs[bcur][0];
            bf16x8 af[4], bfv[4];
#pragma unroll
            for (int m = 0; m < 4; ++m) {
                int r = wrow + m * 16 + c16 + t;
                af[m] = *reinterpret_cast<const bf16x8*>(
                    &Ab[r * 32 + ((g ^ ((r >> 1) & 3)) << 3)]);
            }
#pragma unroll
            for (int n = 0; n < 4; ++n) {
                int rb = wcol + n * 16 + c16;
                bfv[n] = *reinterpret_cast<const bf16x8*>(
                    &Bb[rb * 32 + ((g ^ ((rb >> 1) & 3)) << 3)]);
            }
            __builtin_amdgcn_s_setprio(1);
#pragma unroll
            for (int m = 0; m < 4; ++m)
#pragma unroll
                for (int n = 0; n < 4; ++n)
                    acc[m][n] = __builtin_amdgcn_mfma_f32_16x16x32_bf16(
                        af[m], bfv[n], acc[m][n], 0, 0, 0);
            __builtin_amdgcn_s_setprio(0);
            bcur = bnext;
        }
    }

    // Q branch: fold 1/sqrt(DH) * log2(e) so attn softmax runs in exp2 domain
    float osc = (tensor == 0) ? 0.125f * 1.44269504f : 1.0f;
#pragma unroll
    for (int m = 0; m < 4; ++m) {
        int rowb = s0 + wrow + m * 16 + 4 * g;
#pragma unroll
        for (int n = 0; n < 4; ++n) {
            int col = co0 + wcol + n * 16 + c16;
            float be = b_eff[col];
#pragma unroll
            for (int ri = 0; ri < 4; ++ri)
                out[(size_t)(rowb + ri) * DOUT_ + col] =
                    f2bf((acc[m][n][ri] + be) * osc);
        }
    }
#undef STAGE_A
#undef STAGE_B
}

// ---------------- kernel 2b: transpose V per (b,h): [S][DH] -> [DH][S] --------
__global__ void transpose_v(const unsigned short* __restrict__ vh,
                            unsigned short* __restrict__ vt) {
    __shared__ alignas(16) unsigned short T[64 * 64];
    int bid = blockIdx.x;
    int stile = bid & 31;
    int bh = bid >> 5;
    int b = bh >> 3;
    int h = bh & 7;
    int s0 = stile * 64;
    const unsigned short* src = vh + ((size_t)b * S_ + s0) * DOUT_ + h * DH_;
    unsigned short* dst = vt + (size_t)bh * DH_ * S_ + s0;
    int tid = threadIdx.x;
#pragma unroll
    for (int it = 0; it < 2; ++it) {
        int idx = tid + it * 256;
        int s = idx >> 3, dhc = idx & 7;
        uint4 val = *reinterpret_cast<const uint4*>(&src[(size_t)s * DOUT_ + dhc * 8]);
        *reinterpret_cast<uint4*>(&T[s * 64 + ((dhc ^ (s & 7) ^ ((s >> 3) & 7)) << 3)]) = val;
    }
    __syncthreads();
#pragma unroll
    for (int it = 0; it < 2; ++it) {
        int idx = tid + it * 256;
        int dh = idx >> 3, sc = idx & 7;
        unsigned short tmp[8];
#pragma unroll
        for (int j = 0; j < 8; ++j) {
            int s = sc * 8 + j;
            tmp[j] = T[s * 64 + (((dh >> 3) ^ (s & 7) ^ ((s >> 3) & 7)) << 3) + (dh & 7)];
        }
        *reinterpret_cast<uint4*>(&dst[(size_t)dh * S_ + sc * 8]) =
            *reinterpret_cast<const uint4*>(tmp);
    }
}

// ---------------- kernel 3: flash attention, QBLK=128, K-split x2 (R12) ------
__global__ __launch_bounds__(256, 4) void attn(const unsigned short* __restrict__ qh,
                     const unsigned short* __restrict__ kh,
                     const unsigned short* __restrict__ vt,
                     unsigned short* __restrict__ part,
                     float2* __restrict__ ml) {
    __shared__ alignas(16) unsigned short Ks[2][64 * 64];
    __shared__ alignas(16) unsigned short Vs[2][64 * 64];

    const int tid = threadIdx.x;
    const int l = tid & 63;
    const int wv = tid >> 6;
    const int g = l >> 4;
    const int c16 = l & 15;

    const int bid = blockIdx.x;
    const int ks = bid >> 9;
    const int r9 = bid & 511;
    const int qt = r9 & 15;
    const int bh = r9 >> 4;
    const int b = bh >> 3;
    const int h = bh & 7;
    const int s0 = qt * 128;

    const unsigned short* qp = qh + (size_t)b * S_ * DOUT_ + h * DH_;
    const unsigned short* kp = kh + (size_t)b * S_ * DOUT_ + h * DH_;
    const unsigned short* vp = vt + (size_t)bh * DH_ * S_;

    bf16x8 qfA[2], qfB[2];
    {
        int rowA = s0 + wv * 16 + c16;
        int rowB = rowA + 64;
        qfA[0] = *reinterpret_cast<const bf16x8*>(&qp[(size_t)rowA * DOUT_ + 8 * g]);
        qfA[1] = *reinterpret_cast<const bf16x8*>(&qp[(size_t)rowA * DOUT_ + 32 + 8 * g]);
        qfB[0] = *reinterpret_cast<const bf16x8*>(&qp[(size_t)rowB * DOUT_ + 8 * g]);
        qfB[1] = *reinterpret_cast<const bf16x8*>(&qp[(size_t)rowB * DOUT_ + 32 + 8 * g]);
    }

    const int l3 = l >> 3;
    const int kchunk8 = ((l & 7) ^ l3) * 8;

#define STAGE(kt, buf) do {                                                          \
        const unsigned short* kgp = kp + (size_t)(kt) * 64 * DOUT_;                  \
        const unsigned short* vgp = vp + (size_t)(kt) * 64;                          \
        _Pragma("unroll")                                                            \
        for (int i = 0; i < 2; ++i) {                                                \
            int K0 = wv * 16 + i * 8;                                                \
            gl_lds16(kgp + (size_t)(K0 + l3) * DOUT_ + kchunk8, &Ks[buf][K0 * 64]);  \
            gl_lds16(vgp + (size_t)(K0 + l3) * S_   + kchunk8, &Vs[buf][K0 * 64]);   \
        }                                                                            \
    } while (0)

    f32x4 oaccA[4] = {}, oaccB[4] = {};
    float mrowA = -1e30f, lrowA = 0.f;
    float mrowB = -1e30f, lrowB = 0.f;

    const int sA = ((l & 16) << 1) | c16;
    const int sB = sA + 16;
    const bool hi = (l & 32) != 0;

    const int t0 = ks * 16;
    STAGE(t0, 0);

#define SOFTMAX_GRP(sf, mrow, lrow, oacc, pk) do {                               \
        float u0 = fmaxf(fmaxf(sf[0][0], sf[0][1]), fmaxf(sf[0][2], sf[0][3]));  \
        float u1 = fmaxf(fmaxf(sf[1][0], sf[1][1]), fmaxf(sf[1][2], sf[1][3]));  \
        float u2 = fmaxf(fmaxf(sf[2][0], sf[2][1]), fmaxf(sf[2][2], sf[2][3]));  \
        float u3 = fmaxf(fmaxf(sf[3][0], sf[3][1]), fmaxf(sf[3][2], sf[3][3]));  \
        float m0 = fmaxf(fmaxf(u0, u1), fmaxf(u2, u3));                          \
        m0 = fmaxf(m0, __shfl_xor(m0, 16, 64));                                  \
        m0 = fmaxf(m0, __shfl_xor(m0, 32, 64));                                  \
        if (!__all(m0 <= mrow + 8.f)) {                                          \
            float mnew = fmaxf(mrow, m0);                                        \
            float corr = fexp2(mrow - mnew);                                     \
            mrow = mnew;                                                         \
            lrow *= corr;                                                        \
            _Pragma("unroll")                                                    \
            for (int n = 0; n < 4; ++n) {                                        \
                oacc[n][0] *= corr; oacc[n][1] *= corr;                          \
                oacc[n][2] *= corr; oacc[n][3] *= corr;                          \
            }                                                                    \
        }                                                                        \
        float rsacc = 0.f;                                                       \
        _Pragma("unroll")                                                        \
        for (int n = 0; n < 4; ++n) {                                            \
            float p0 = fexp2(sf[n][0] - mrow);                                   \
            float p1 = fexp2(sf[n][1] - mrow);                                   \
            float p2 = fexp2(sf[n][2] - mrow);                                   \
            float p3 = fexp2(sf[n][3] - mrow);                                   \
            rsacc += (p0 + p1) + (p2 + p3);                                      \
            pk[n][0] = cvt2(p0, p1);                                             \
            pk[n][1] = cvt2(p2, p3);                                             \
        }                                                                        \
        rsacc += __shfl_xor(rsacc, 16, 64);                                      \
        rsacc += __shfl_xor(rsacc, 32, 64);                                      \
        lrow += rsacc;                                                           \
    } while (0)

#define BUILD_PU(pk, kk, pu) do {                                                \
        unsigned a0 = __shfl((int)pk[2 * (kk)][0], sA, 64);                      \
        unsigned a1 = __shfl((int)pk[2 * (kk)][1], sA, 64);                      \
        unsigned a2 = __shfl((int)pk[2 * (kk)][0], sB, 64);                      \
        unsigned a3 = __shfl((int)pk[2 * (kk)][1], sB, 64);                      \
        unsigned b0 = __shfl((int)pk[2 * (kk) + 1][0], sA, 64);                  \
        unsigned b1 = __shfl((int)pk[2 * (kk) + 1][1], sA, 64);                  \
        unsigned b2 = __shfl((int)pk[2 * (kk) + 1][0], sB, 64);                  \
        unsigned b3 = __shfl((int)pk[2 * (kk) + 1][1], sB, 64);                  \
        pu.w[0] = hi ? b0 : a0;                                                  \
        pu.w[1] = hi ? b1 : a1;                                                  \
        pu.w[2] = hi ? b2 : a2;                                                  \
        pu.w[3] = hi ? b3 : a3;                                                  \
    } while (0)

    for (int i = 0; i < 16; ++i) {
        const int cur = i & 1;
        if (i + 1 < 16) {
            STAGE(t0 + i + 1, 1 - cur);
            asm volatile("s_waitcnt vmcnt(4)" ::: "memory");
        } else {
            asm volatile("s_waitcnt vmcnt(0)" ::: "memory");
        }
        __builtin_amdgcn_s_barrier();

        const char* KsB = (const char*)&Ks[cur][0];
        f32x4 sfA[4] = {}, sfB[4] = {};
#pragma unroll
        for (int kk = 0; kk < 2; ++kk) {
            bf16x8 kf[4];
#pragma unroll
            for (int n = 0; n < 4; ++n)
                kf[n] = *reinterpret_cast<const bf16x8*>(
                    KsB + (n * 16 + c16) * 128 + (((4 * kk + g) ^ (l & 7)) << 4));
            __builtin_amdgcn_s_setprio(1);
#pragma unroll
            for (int n = 0; n < 4; ++n) {
                sfA[n] = __builtin_amdgcn_mfma_f32_16x16x32_bf16(kf[n], qfA[kk], sfA[n], 0, 0, 0);
                sfB[n] = __builtin_amdgcn_mfma_f32_16x16x32_bf16(kf[n], qfB[kk], sfB[n], 0, 0, 0);
            }
            __builtin_amdgcn_s_setprio(0);
        }

        unsigned pkA[4][2], pkB[4][2];
        SOFTMAX_GRP(sfA, mrowA, lrowA, oaccA, pkA);
        SOFTMAX_GRP(sfB, mrowB, lrowB, oaccB, pkB);

        const char* VsB = (const char*)&Vs[cur][0];
#pragma unroll
        for (int kk = 0; kk < 2; ++kk) {
            union { unsigned w[4]; bf16x8 v; } puA, puB;
            BUILD_PU(pkA, kk, puA);
            BUILD_PU(pkB, kk, puB);
            bf16x8 vfr[4];
#pragma unroll
            for (int n = 0; n < 4; ++n)
                vfr[n] = *reinterpret_cast<const bf16x8*>(
                    VsB + (n * 16 + c16) * 128 + (((4 * kk + g) ^ (l & 7)) << 4));
            __builtin_amdgcn_s_setprio(1);
#pragma unroll
            for (int n = 0; n < 4; ++n) {
                oaccA[n] = __builtin_amdgcn_mfma_f32_16x16x32_bf16(vfr[n], puA.v, oaccA[n], 0, 0, 0);
                oaccB[n] = __builtin_amdgcn_mfma_f32_16x16x32_bf16(vfr[n], puB.v, oaccB[n], 0, 0, 0);
            }
            __builtin_amdgcn_s_setprio(0);
        }
        __builtin_amdgcn_s_barrier();
    }

    {
        int rowA = s0 + wv * 16 + c16;
        int rowB = rowA + 64;
        unsigned short* ppA = part + (((size_t)ks * 32 + bh) * S_ + rowA) * DH_;
        unsigned short* ppB = part + (((size_t)ks * 32 + bh) * S_ + rowB) * DH_;
#pragma unroll
        for (int n = 0; n < 4; ++n) {
            uint2 wA, wB;
            wA.x = cvt2(oaccA[n][0], oaccA[n][1]);
            wA.y = cvt2(oaccA[n][2], oaccA[n][3]);
            wB.x = cvt2(oaccB[n][0], oaccB[n][1]);
            wB.y = cvt2(oaccB[n][2], oaccB[n][3]);
            *reinterpret_cast<uint2*>(&ppA[n * 16 + 4 * g]) = wA;
            *reinterpret_cast<uint2*>(&ppB[n * 16 + 4 * g]) = wB;
        }
        if (g == 0) {
            ml[((size_t)ks * 32 + bh) * S_ + rowA] = make_float2(mrowA, lrowA);
            ml[((size_t)ks * 32 + bh) * S_ + rowB] = make_float2(mrowB, lrowB);
        }
    }
#undef STAGE
#undef SOFTMAX_GRP
#undef BUILD_PU
}

// ---------------- kernel 4: combine K-split partials + LayerNorm -------------
__global__ void combine_ln(const unsigned short* __restrict__ part,
                           const float2* __restrict__ ml,
                           const float* __restrict__ gamma,
                           const float* __restrict__ beta,
                           float* __restrict__ out) {
    int tid = threadIdx.x;
    int lane = tid & 63;
    int wv = tid >> 6;
    int row = blockIdx.x * 4 + wv;          // 0 .. B*S-1
    int b = row >> 11;
    int q = row & 2047;
    int h = lane >> 3;
    int dh0 = (lane & 7) * 8;

    size_t idx0 = ((size_t)(b * 8 + h)) * S_ + q;
    size_t idx1 = ((size_t)32 + b * 8 + h) * S_ + q;
    uint4 r0 = *reinterpret_cast<const uint4*>(&part[idx0 * DH_ + dh0]);
    uint4 r1 = *reinterpret_cast<const uint4*>(&part[idx1 * DH_ + dh0]);
    float2 ml0 = ml[idx0];
    float2 ml1 = ml[idx1];

    float m = fmaxf(ml0.x, ml1.x);
    float w0 = fexp2(ml0.x - m);
    float w1 = fexp2(ml1.x - m);
    float linv = 1.0f / (w0 * ml0.y + w1 * ml1.y);

    const unsigned short* e0 = reinterpret_cast<const unsigned short*>(&r0);
    const unsigned short* e1 = reinterpret_cast<const unsigned short*>(&r1);
    float o[8];
    float s = 0.f, sq = 0.f;
#pragma unroll
    for (int j = 0; j < 8; ++j) {
        float v = (w0 * bf2f(e0[j]) + w1 * bf2f(e1[j])) * linv;
        o[j] = v;
        s += v;
        sq += v * v;
    }
    for (int off = 1; off < 64; off <<= 1) {
        s += __shfl_xor(s, off, 64);
        sq += __shfl_xor(sq, off, 64);
    }
    float mu = s * (1.0f / 512.0f);
    float var = sq * (1.0f / 512.0f) - mu * mu;
    float rstd = rsqrtf(fmaxf(var, 0.f) + EPS_);

    int f0 = lane * 8;
    float4 g0 = *reinterpret_cast<const float4*>(&gamma[f0]);
    float4 g1 = *reinterpret_cast<const float4*>(&gamma[f0 + 4]);
    float4 b0 = *reinterpret_cast<const float4*>(&beta[f0]);
    float4 b1 = *reinterpret_cast<const float4*>(&beta[f0 + 4]);
    float4 o0, o1;
    o0.x = (o[0] - mu) * rstd * g0.x + b0.x;
    o0.y = (o[1] - mu) * rstd * g0.y + b0.y;
    o0.z = (o[2] - mu) * rstd * g0.z + b0.z;
    o0.w = (o[3] - mu) * rstd * g0.w + b0.w;
    o1.x = (o[4] - mu) * rstd * g1.x + b1.x;
    o1.y = (o[5] - mu) * rstd * g1.y + b1.y;
    o1.z = (o[6] - mu) * rstd * g1.z + b1.z;
    o1.w = (o[7] - mu) * rstd * g1.w + b1.w;
    float* op = out + (size_t)row * DOUT_ + f0;
    *reinterpret_cast<float4*>(op) = o0;
    *reinterpret_cast<float4*>(op + 4) = o1;
}

extern "C" void kernel_launch(void* const* d_in, const int* in_sizes, int n_in,
                              void* d_out, int out_size, void* d_ws, size_t ws_size,
                              hipStream_t stream) {
    const float* q        = (const float*)d_in[0];
    const float* k        = (const float*)d_in[1];
    const float* v        = (const float*)d_in[2];
    const float* conv_w   = (const float*)d_in[3];
    const float* conv_b   = (const float*)d_in[4];
    const float* bn_gamma = (const float*)d_in[5];
    const float* bn_beta  = (const float*)d_in[6];
    const float* bn_mean  = (const float*)d_in[7];
    const float* bn_var   = (const float*)d_in[8];
    const float* ln_gamma = (const float*)d_in[9];
    const float* ln_beta  = (const float*)d_in[10];

    unsigned short* qh    = (unsigned short*)d_ws;
    unsigned short* kh    = qh + (size_t)B_ * S_ * DOUT_;
    unsigned short* vh    = kh + (size_t)B_ * S_ * DOUT_;
    unsigned short* w_eff = vh + (size_t)B_ * S_ * DOUT_;
    float* b_eff          = (float*)(w_eff + (size_t)7 * DOUT_ * DIN_);
    unsigned short* xb    = (unsigned short*)(b_eff + DOUT_);
    unsigned short* vt    = xb;   // alias: vt written only after conv consumed xb
    unsigned short* part  = xb + (size_t)12 * SP_ * DIN_;
    float2* ml            = (float2*)(part + (size_t)2 * B_ * H_ * S_ * DH_);

    float* out = (float*)d_out;

    cast_x<<<dim3(6162), dim3(256), 0, stream>>>(q, k, v, xb);
    prep_w<<<dim3(7168), dim3(256), 0, stream>>>(conv_w, conv_b, bn_gamma, bn_beta,
                                                 bn_mean, bn_var, w_eff, b_eff);
    conv_bn<<<dim3(768), dim3(256), 0, stream>>>(xb, w_eff, b_eff, qh);
    transpose_v<<<dim3(1024), dim3(256), 0, stream>>>(vh, vt);
    attn<<<dim3(1024), dim3(256), 0, stream>>>(qh, kh, vt, part, ml);
    combine_ln<<<dim3(2048), dim3(256), 0, stream>>>(part, ml, ln_gamma, ln_beta, out);
}